// Round 1
// baseline (2593.144 us; speedup 1.0000x reference)
//
#include <hip/hip_runtime.h>

#define D 128

// ---- degree count: one thread per edge, int atomic on cnt[dst] ----
__global__ void count_kernel(const int* __restrict__ ei, int E, int* __restrict__ cnt) {
    int t = blockIdx.x * blockDim.x + threadIdx.x;
    if (t < E) atomicAdd(&cnt[ei[E + t]], 1);
}

__global__ void inv_kernel(const int* __restrict__ cnt, float* __restrict__ inv, int N) {
    int t = blockIdx.x * blockDim.x + threadIdx.x;
    if (t < N) inv[t] = 1.0f / (float)max(cnt[t], 1);
}

// ---- scatter-add: 32 threads per edge, float4 gather + 4 fp32 atomics ----
__global__ void scatter_kernel(const float* __restrict__ x, const int* __restrict__ ei,
                               int E, float* __restrict__ agg) {
    long long t = (long long)blockIdx.x * blockDim.x + threadIdx.x;
    if (t >= (long long)E * 32) return;
    int e = (int)(t >> 5), c = (int)(t & 31);
    int src = ei[e], dst = ei[E + e];
    float4 v = ((const float4*)(x + (size_t)src * D))[c];
    float* p = agg + (size_t)dst * D + (size_t)c * 4;
    unsafeAtomicAdd(p + 0, v.x);
    unsafeAtomicAdd(p + 1, v.y);
    unsafeAtomicAdd(p + 2, v.z);
    unsafeAtomicAdd(p + 3, v.w);
}

// ---- fused: out = relu(l2norm(mean_agg @ Wl + bl + x @ Wr)) [@ Wf + bf] ----
// one block (128 threads) per node; node rows staged in LDS, W from L2.
template <int FUSE_FC>
__global__ void linear_kernel(const float* __restrict__ agg, const float* __restrict__ inv,
                              const float* __restrict__ x,
                              const float* __restrict__ Wl, const float* __restrict__ bl,
                              const float* __restrict__ Wr,
                              const float* __restrict__ Wf, const float* __restrict__ bf,
                              float* __restrict__ out) {
    __shared__ float sa[D], sx[D], so[D];
    __shared__ float sred[2];
    int node = blockIdx.x;
    int j = threadIdx.x;
    sa[j] = agg[(size_t)node * D + j] * inv[node];
    sx[j] = x[(size_t)node * D + j];
    __syncthreads();

    float acc = bl[j];
#pragma unroll 8
    for (int k = 0; k < D; k++)
        acc = fmaf(sa[k], Wl[k * D + j], fmaf(sx[k], Wr[k * D + j], acc));

    // block-wide L2 norm over the 128 outputs
    float v = acc * acc;
#pragma unroll
    for (int o = 32; o > 0; o >>= 1) v += __shfl_down(v, o);  // wave64 reduce
    if ((j & 63) == 0) sred[j >> 6] = v;
    __syncthreads();
    float nrm = sqrtf(sred[0] + sred[1]);
    float h = acc / fmaxf(nrm, 1e-12f);
    h = fmaxf(h, 0.0f);  // relu

    if (FUSE_FC) {
        so[j] = h;
        __syncthreads();
        float o2 = bf[j];
#pragma unroll 8
        for (int k = 0; k < D; k++) o2 = fmaf(so[k], Wf[k * D + j], o2);
        out[(size_t)node * D + j] = o2;
    } else {
        out[(size_t)node * D + j] = h;
    }
}

extern "C" void kernel_launch(void* const* d_in, const int* in_sizes, int n_in,
                              void* d_out, int out_size, void* d_ws, size_t ws_size,
                              hipStream_t stream) {
    const float* x   = (const float*)d_in[0];
    const int*   ei  = (const int*)d_in[1];
    const float* W1l = (const float*)d_in[2];
    const float* b1  = (const float*)d_in[3];
    const float* W1r = (const float*)d_in[4];
    const float* W2l = (const float*)d_in[5];
    const float* b2  = (const float*)d_in[6];
    const float* W2r = (const float*)d_in[7];
    const float* Wf  = (const float*)d_in[8];
    const float* bf  = (const float*)d_in[9];
    float* out = (float*)d_out;

    int N = in_sizes[0] / D;
    int E = in_sizes[1] / 2;

    // workspace layout (floats): cnt[N] (as int) | inv[N] | agg[N*D] | h1[N*D]
    float* ws  = (float*)d_ws;
    int*   cnt = (int*)ws;
    float* inv = ws + N;
    float* agg = ws + 2 * (size_t)N;
    float* h1  = agg + (size_t)N * D;

    hipMemsetAsync(cnt, 0, (size_t)N * sizeof(int), stream);
    hipMemsetAsync(agg, 0, (size_t)N * D * sizeof(float), stream);

    count_kernel<<<(E + 255) / 256, 256, 0, stream>>>(ei, E, cnt);
    inv_kernel<<<(N + 255) / 256, 256, 0, stream>>>(cnt, inv, N);

    long long sthreads = (long long)E * 32;
    int sblocks = (int)((sthreads + 255) / 256);

    // layer 1
    scatter_kernel<<<sblocks, 256, 0, stream>>>(x, ei, E, agg);
    linear_kernel<0><<<N, D, 0, stream>>>(agg, inv, x, W1l, b1, W1r, nullptr, nullptr, h1);

    // layer 2 (+ fused final fc)
    hipMemsetAsync(agg, 0, (size_t)N * D * sizeof(float), stream);
    scatter_kernel<<<sblocks, 256, 0, stream>>>(h1, ei, E, agg);
    linear_kernel<1><<<N, D, 0, stream>>>(agg, inv, h1, W2l, b2, W2r, Wf, bf, out);
}

// Round 2
// 727.667 us; speedup vs baseline: 3.5636x; 3.5636x over previous
//
#include <hip/hip_runtime.h>

#define D 128
#define NODES 50000
#define SCAN_B 256

// ---- degree count ----
__global__ void count_kernel(const int* __restrict__ ei, int E, int* __restrict__ cnt) {
    int t = blockIdx.x * blockDim.x + threadIdx.x;
    if (t < E) atomicAdd(&cnt[ei[E + t]], 1);
}

__global__ void inv_kernel(const int* __restrict__ cnt, float* __restrict__ inv, int N) {
    int t = blockIdx.x * blockDim.x + threadIdx.x;
    if (t < N) inv[t] = 1.0f / (float)max(cnt[t], 1);
}

// ---- hierarchical exclusive scan over cnt[N] -> rs[N], block sums -> bsum ----
__global__ void scan_pass1(const int* __restrict__ cnt, int* __restrict__ rs,
                           int* __restrict__ bsum, int N) {
    __shared__ int lds[SCAN_B];
    int tid = threadIdx.x;
    int i = blockIdx.x * SCAN_B + tid;
    int v = (i < N) ? cnt[i] : 0;
    lds[tid] = v;
    __syncthreads();
    for (int o = 1; o < SCAN_B; o <<= 1) {
        int t = (tid >= o) ? lds[tid - o] : 0;
        __syncthreads();
        lds[tid] += t;
        __syncthreads();
    }
    if (i < N) rs[i] = lds[tid] - v;  // exclusive
    if (tid == SCAN_B - 1) bsum[blockIdx.x] = lds[tid];
}

__global__ void scan_pass2(int* __restrict__ bsum, int nb) {
    __shared__ int lds[SCAN_B];
    int tid = threadIdx.x;
    int v = (tid < nb) ? bsum[tid] : 0;
    lds[tid] = v;
    __syncthreads();
    for (int o = 1; o < SCAN_B; o <<= 1) {
        int t = (tid >= o) ? lds[tid - o] : 0;
        __syncthreads();
        lds[tid] += t;
        __syncthreads();
    }
    if (tid < nb) bsum[tid] = lds[tid] - v;  // exclusive
}

__global__ void scan_pass3(int* __restrict__ rs, int* __restrict__ cursor,
                           const int* __restrict__ bsum, int N) {
    int i = blockIdx.x * SCAN_B + threadIdx.x;
    if (i < N) {
        int v = rs[i] + bsum[blockIdx.x];
        rs[i] = v;
        cursor[i] = v;
    }
}

// ---- fill CSR adjacency: csr[rs[dst] ...] = srcs ----
__global__ void fill_kernel(const int* __restrict__ ei, int E,
                            int* __restrict__ cursor, int* __restrict__ csr) {
    int e = blockIdx.x * blockDim.x + threadIdx.x;
    if (e < E) {
        int src = ei[e], dst = ei[E + e];
        int pos = atomicAdd(&cursor[dst], 1);
        csr[pos] = src;
    }
}

// ---- gather-mean aggregate: 32 threads (float4 lanes) per node ----
__global__ void aggregate_kernel(const float* __restrict__ x, const int* __restrict__ csr,
                                 const int* __restrict__ rs, const int* __restrict__ cnt,
                                 const float* __restrict__ inv, float* __restrict__ agg,
                                 int N) {
    int t = blockIdx.x * blockDim.x + threadIdx.x;
    int node = t >> 5;
    int c = t & 31;
    if (node >= N) return;
    int deg = cnt[node];
    int st = rs[node];
    float4 s = make_float4(0.f, 0.f, 0.f, 0.f);
    const float4* x4 = (const float4*)x;
    for (int i = 0; i < deg; i++) {
        int nbr = csr[st + i];
        float4 v = x4[(size_t)nbr * 32 + c];
        s.x += v.x; s.y += v.y; s.z += v.z; s.w += v.w;
    }
    float iv = inv[node];
    s.x *= iv; s.y *= iv; s.z *= iv; s.w *= iv;
    ((float4*)agg)[(size_t)node * 32 + c] = s;
}

// ---- fused: out = relu(l2norm(agg @ Wl + bl + x @ Wr)) [@ Wf + bf] ----
template <int FUSE_FC>
__global__ void linear_kernel(const float* __restrict__ agg,
                              const float* __restrict__ x,
                              const float* __restrict__ Wl, const float* __restrict__ bl,
                              const float* __restrict__ Wr,
                              const float* __restrict__ Wf, const float* __restrict__ bf,
                              float* __restrict__ out) {
    __shared__ float sa[D], sx[D], so[D];
    __shared__ float sred[2];
    int node = blockIdx.x;
    int j = threadIdx.x;
    sa[j] = agg[(size_t)node * D + j];
    sx[j] = x[(size_t)node * D + j];
    __syncthreads();

    float acc = bl[j];
#pragma unroll 8
    for (int k = 0; k < D; k++)
        acc = fmaf(sa[k], Wl[k * D + j], fmaf(sx[k], Wr[k * D + j], acc));

    float v = acc * acc;
#pragma unroll
    for (int o = 32; o > 0; o >>= 1) v += __shfl_down(v, o);
    if ((j & 63) == 0) sred[j >> 6] = v;
    __syncthreads();
    float nrm = sqrtf(sred[0] + sred[1]);
    float h = acc / fmaxf(nrm, 1e-12f);
    h = fmaxf(h, 0.0f);

    if (FUSE_FC) {
        so[j] = h;
        __syncthreads();
        float o2 = bf[j];
#pragma unroll 8
        for (int k = 0; k < D; k++) o2 = fmaf(so[k], Wf[k * D + j], o2);
        out[(size_t)node * D + j] = o2;
    } else {
        out[(size_t)node * D + j] = h;
    }
}

extern "C" void kernel_launch(void* const* d_in, const int* in_sizes, int n_in,
                              void* d_out, int out_size, void* d_ws, size_t ws_size,
                              hipStream_t stream) {
    const float* x   = (const float*)d_in[0];
    const int*   ei  = (const int*)d_in[1];
    const float* W1l = (const float*)d_in[2];
    const float* b1  = (const float*)d_in[3];
    const float* W1r = (const float*)d_in[4];
    const float* W2l = (const float*)d_in[5];
    const float* b2  = (const float*)d_in[6];
    const float* W2r = (const float*)d_in[7];
    const float* Wf  = (const float*)d_in[8];
    const float* bf  = (const float*)d_in[9];
    float* out = (float*)d_out;

    int N = in_sizes[0] / D;
    int E = in_sizes[1] / 2;

    // ws layout: agg[N*D] f | inv[N] f | rs[N] i | cnt[N] i | cursor[N] i | bsum[256] i | csr[E] i
    float* ws     = (float*)d_ws;
    float* agg    = ws;
    float* inv    = ws + (size_t)N * D;
    int*   rs     = (int*)(inv + N);
    int*   cnt    = rs + N;
    int*   cursor = cnt + N;
    int*   bsum   = cursor + N;
    int*   csr    = bsum + 256;

    int nb = (N + SCAN_B - 1) / SCAN_B;  // 196

    hipMemsetAsync(cnt, 0, (size_t)N * sizeof(int), stream);
    count_kernel<<<(E + 255) / 256, 256, 0, stream>>>(ei, E, cnt);
    inv_kernel<<<nb, SCAN_B, 0, stream>>>(cnt, inv, N);
    scan_pass1<<<nb, SCAN_B, 0, stream>>>(cnt, rs, bsum, N);
    scan_pass2<<<1, SCAN_B, 0, stream>>>(bsum, nb);
    scan_pass3<<<nb, SCAN_B, 0, stream>>>(rs, cursor, bsum, N);
    fill_kernel<<<(E + 255) / 256, 256, 0, stream>>>(ei, E, cursor, csr);

    int agg_blocks = (N * 32 + 255) / 256;

    // layer 1  (h1 lives in d_out)
    aggregate_kernel<<<agg_blocks, 256, 0, stream>>>(x, csr, rs, cnt, inv, agg, N);
    linear_kernel<0><<<N, D, 0, stream>>>(agg, x, W1l, b1, W1r, nullptr, nullptr, out);

    // layer 2 (+ fused final fc): reads h1 from d_out, overwrites d_out
    aggregate_kernel<<<agg_blocks, 256, 0, stream>>>(out, csr, rs, cnt, inv, agg, N);
    linear_kernel<1><<<N, D, 0, stream>>>(agg, out, W2l, b2, W2r, Wf, bf, out);
}

// Round 3
// 394.657 us; speedup vs baseline: 6.5706x; 1.8438x over previous
//
#include <hip/hip_runtime.h>

#define D 128
#define SCAN_B 256
#define BM 64
#define BK 32
// As stride padded to 68 floats (16B-aligned rows, bank-spread for transposed stores)
#define AS_LD 68
#define HS_LD 132

// ---- degree count ----
__global__ void count_kernel(const int* __restrict__ ei, int E, int* __restrict__ cnt) {
    int t = blockIdx.x * blockDim.x + threadIdx.x;
    if (t < E) atomicAdd(&cnt[ei[E + t]], 1);
}

__global__ void inv_kernel(const int* __restrict__ cnt, float* __restrict__ inv, int N) {
    int t = blockIdx.x * blockDim.x + threadIdx.x;
    if (t < N) inv[t] = 1.0f / (float)max(cnt[t], 1);
}

// ---- hierarchical exclusive scan ----
__global__ void scan_pass1(const int* __restrict__ cnt, int* __restrict__ rs,
                           int* __restrict__ bsum, int N) {
    __shared__ int lds[SCAN_B];
    int tid = threadIdx.x;
    int i = blockIdx.x * SCAN_B + tid;
    int v = (i < N) ? cnt[i] : 0;
    lds[tid] = v;
    __syncthreads();
    for (int o = 1; o < SCAN_B; o <<= 1) {
        int t = (tid >= o) ? lds[tid - o] : 0;
        __syncthreads();
        lds[tid] += t;
        __syncthreads();
    }
    if (i < N) rs[i] = lds[tid] - v;
    if (tid == SCAN_B - 1) bsum[blockIdx.x] = lds[tid];
}

__global__ void scan_pass2(int* __restrict__ bsum, int nb) {
    __shared__ int lds[SCAN_B];
    int tid = threadIdx.x;
    int v = (tid < nb) ? bsum[tid] : 0;
    lds[tid] = v;
    __syncthreads();
    for (int o = 1; o < SCAN_B; o <<= 1) {
        int t = (tid >= o) ? lds[tid - o] : 0;
        __syncthreads();
        lds[tid] += t;
        __syncthreads();
    }
    if (tid < nb) bsum[tid] = lds[tid] - v;
}

__global__ void scan_pass3(int* __restrict__ rs, int* __restrict__ cursor,
                           const int* __restrict__ bsum, int N) {
    int i = blockIdx.x * SCAN_B + threadIdx.x;
    if (i < N) {
        int v = rs[i] + bsum[blockIdx.x];
        rs[i] = v;
        cursor[i] = v;
    }
}

__global__ void fill_kernel(const int* __restrict__ ei, int E,
                            int* __restrict__ cursor, int* __restrict__ csr) {
    int e = blockIdx.x * blockDim.x + threadIdx.x;
    if (e < E) {
        int src = ei[e], dst = ei[E + e];
        int pos = atomicAdd(&cursor[dst], 1);
        csr[pos] = src;
    }
}

// ---- gather-mean aggregate: 32 threads (float4 lanes) per node ----
__global__ void aggregate_kernel(const float* __restrict__ x, const int* __restrict__ csr,
                                 const int* __restrict__ rs, const int* __restrict__ cnt,
                                 const float* __restrict__ inv, float* __restrict__ agg,
                                 int N) {
    int t = blockIdx.x * blockDim.x + threadIdx.x;
    int node = t >> 5;
    int c = t & 31;
    if (node >= N) return;
    int deg = cnt[node];
    int st = rs[node];
    float4 s = make_float4(0.f, 0.f, 0.f, 0.f);
    const float4* x4 = (const float4*)x;
    for (int i = 0; i < deg; i++) {
        int nbr = csr[st + i];
        float4 v = x4[(size_t)nbr * 32 + c];
        s.x += v.x; s.y += v.y; s.z += v.z; s.w += v.w;
    }
    float iv = inv[node];
    s.x *= iv; s.y *= iv; s.z *= iv; s.w *= iv;
    ((float4*)agg)[(size_t)node * 32 + c] = s;
}

// ---- register-tiled fused GEMM ----
// C[64 nodes x 128] = relu(l2norm([agg|x] @ [Wl;Wr] + bl)) [@ Wf + bf]
// 256 threads: thread -> (tg = tid>>5 -> 8 nodes, tn = tid&31 -> 4 cols)
template <int FUSE_FC>
__global__ __launch_bounds__(256) void gemm_kernel(
        const float* __restrict__ agg, const float* x,
        const float* __restrict__ Wl, const float* __restrict__ bl,
        const float* __restrict__ Wr,
        const float* __restrict__ Wf, const float* __restrict__ bf,
        float* out, int N) {
    __shared__ float As[BK * AS_LD];          // A transposed: As[k][m]
    __shared__ float Ws[BK * D];              // W: Ws[k][n]
    __shared__ float Hs[FUSE_FC ? BM * HS_LD : 1];

    const int tid = threadIdx.x;
    const int tn = tid & 31;
    const int tg = tid >> 5;
    const int m_base = tg * 8;
    const int n_base = tn * 4;
    const int mb = blockIdx.x * BM;

    float acc[8][4];
#pragma unroll
    for (int i = 0; i < 8; i++)
#pragma unroll
        for (int j = 0; j < 4; j++) acc[i][j] = 0.0f;

    for (int kk = 0; kk < 2 * D; kk += BK) {
        const float* Ab = (kk < D) ? agg : x;
        const float* Wb = (kk < D) ? Wl : Wr;
        const int kl = kk & (D - 1);
        // stage A tile transposed: 512 float4 reads -> scalar scattered stores
#pragma unroll
        for (int r = 0; r < 2; r++) {
            int f = tid + r * 256;
            int m = f >> 3, kq = f & 7;
            int ng = mb + m;
            if (ng >= N) ng = N - 1;
            float4 v = ((const float4*)Ab)[(size_t)ng * 32 + (kl >> 2) + kq];
            float* dst = &As[(kq * 4) * AS_LD + m];
            dst[0] = v.x; dst[AS_LD] = v.y; dst[2 * AS_LD] = v.z; dst[3 * AS_LD] = v.w;
        }
        // stage W tile: straight copy
#pragma unroll
        for (int r = 0; r < 4; r++) {
            int f = tid + r * 256;
            int k = f >> 5, nq = f & 31;
            ((float4*)Ws)[k * 32 + nq] = ((const float4*)Wb)[(size_t)(kl + k) * 32 + nq];
        }
        __syncthreads();
#pragma unroll 4
        for (int k = 0; k < BK; k++) {
            float4 a0 = *((const float4*)&As[k * AS_LD + m_base]);
            float4 a1 = *((const float4*)&As[k * AS_LD + m_base + 4]);
            float4 w  = *((const float4*)&Ws[k * D + n_base]);
            float am[8] = {a0.x, a0.y, a0.z, a0.w, a1.x, a1.y, a1.z, a1.w};
            float wn[4] = {w.x, w.y, w.z, w.w};
#pragma unroll
            for (int mi = 0; mi < 8; mi++)
#pragma unroll
                for (int ni = 0; ni < 4; ni++)
                    acc[mi][ni] = fmaf(am[mi], wn[ni], acc[mi][ni]);
        }
        __syncthreads();
    }

    // epilogue: bias + per-node L2 norm (32-lane reduction) + relu
    const float4 blv = ((const float4*)bl)[tn];
    float h[8][4];
#pragma unroll
    for (int mi = 0; mi < 8; mi++) {
        float v0 = acc[mi][0] + blv.x;
        float v1 = acc[mi][1] + blv.y;
        float v2 = acc[mi][2] + blv.z;
        float v3 = acc[mi][3] + blv.w;
        float s = v0 * v0 + v1 * v1 + v2 * v2 + v3 * v3;
#pragma unroll
        for (int o = 16; o > 0; o >>= 1) s += __shfl_xor(s, o, 32);
        float rn = 1.0f / fmaxf(sqrtf(s), 1e-12f);
        h[mi][0] = fmaxf(v0 * rn, 0.0f);
        h[mi][1] = fmaxf(v1 * rn, 0.0f);
        h[mi][2] = fmaxf(v2 * rn, 0.0f);
        h[mi][3] = fmaxf(v3 * rn, 0.0f);
    }

    if (!FUSE_FC) {
#pragma unroll
        for (int mi = 0; mi < 8; mi++) {
            int node = mb + m_base + mi;
            if (node < N) {
                float4 o4 = make_float4(h[mi][0], h[mi][1], h[mi][2], h[mi][3]);
                ((float4*)out)[(size_t)node * 32 + tn] = o4;
            }
        }
        return;
    }

    // FC: h (in LDS) @ Wf + bf
#pragma unroll
    for (int mi = 0; mi < 8; mi++) {
        float4 o4 = make_float4(h[mi][0], h[mi][1], h[mi][2], h[mi][3]);
        *((float4*)&Hs[(m_base + mi) * HS_LD + n_base]) = o4;
    }

    const float4 bfv = ((const float4*)bf)[tn];
    float acc2[8][4];
#pragma unroll
    for (int mi = 0; mi < 8; mi++) {
        acc2[mi][0] = bfv.x; acc2[mi][1] = bfv.y;
        acc2[mi][2] = bfv.z; acc2[mi][3] = bfv.w;
    }

    for (int kk = 0; kk < D; kk += BK) {
#pragma unroll
        for (int r = 0; r < 4; r++) {
            int f = tid + r * 256;
            int k = f >> 5, nq = f & 31;
            ((float4*)Ws)[k * 32 + nq] = ((const float4*)Wf)[(size_t)(kk + k) * 32 + nq];
        }
        __syncthreads();
#pragma unroll 4
        for (int k = 0; k < BK; k++) {
            float4 w = *((const float4*)&Ws[k * D + n_base]);
            float wn[4] = {w.x, w.y, w.z, w.w};
#pragma unroll
            for (int mi = 0; mi < 8; mi++) {
                float a = Hs[(m_base + mi) * HS_LD + kk + k];
#pragma unroll
                for (int ni = 0; ni < 4; ni++)
                    acc2[mi][ni] = fmaf(a, wn[ni], acc2[mi][ni]);
            }
        }
        __syncthreads();
    }

#pragma unroll
    for (int mi = 0; mi < 8; mi++) {
        int node = mb + m_base + mi;
        if (node < N) {
            float4 o4 = make_float4(acc2[mi][0], acc2[mi][1], acc2[mi][2], acc2[mi][3]);
            ((float4*)out)[(size_t)node * 32 + tn] = o4;
        }
    }
}

extern "C" void kernel_launch(void* const* d_in, const int* in_sizes, int n_in,
                              void* d_out, int out_size, void* d_ws, size_t ws_size,
                              hipStream_t stream) {
    const float* x   = (const float*)d_in[0];
    const int*   ei  = (const int*)d_in[1];
    const float* W1l = (const float*)d_in[2];
    const float* b1  = (const float*)d_in[3];
    const float* W1r = (const float*)d_in[4];
    const float* W2l = (const float*)d_in[5];
    const float* b2  = (const float*)d_in[6];
    const float* W2r = (const float*)d_in[7];
    const float* Wf  = (const float*)d_in[8];
    const float* bf  = (const float*)d_in[9];
    float* out = (float*)d_out;

    int N = in_sizes[0] / D;
    int E = in_sizes[1] / 2;

    // ws layout: agg[N*D] f | inv[N] f | rs[N] i | cnt[N] i | cursor[N] i | bsum[256] i | csr[E] i
    float* ws     = (float*)d_ws;
    float* agg    = ws;
    float* inv    = ws + (size_t)N * D;
    int*   rs     = (int*)(inv + N);
    int*   cnt    = rs + N;
    int*   cursor = cnt + N;
    int*   bsum   = cursor + N;
    int*   csr    = bsum + 256;

    int nb = (N + SCAN_B - 1) / SCAN_B;

    hipMemsetAsync(cnt, 0, (size_t)N * sizeof(int), stream);
    count_kernel<<<(E + 255) / 256, 256, 0, stream>>>(ei, E, cnt);
    inv_kernel<<<nb, SCAN_B, 0, stream>>>(cnt, inv, N);
    scan_pass1<<<nb, SCAN_B, 0, stream>>>(cnt, rs, bsum, N);
    scan_pass2<<<1, SCAN_B, 0, stream>>>(bsum, nb);
    scan_pass3<<<nb, SCAN_B, 0, stream>>>(rs, cursor, bsum, N);
    fill_kernel<<<(E + 255) / 256, 256, 0, stream>>>(ei, E, cursor, csr);

    int agg_blocks = (N * 32 + 255) / 256;
    int gemm_blocks = (N + BM - 1) / BM;

    // layer 1 (h1 lives in d_out)
    aggregate_kernel<<<agg_blocks, 256, 0, stream>>>(x, csr, rs, cnt, inv, agg, N);
    gemm_kernel<0><<<gemm_blocks, 256, 0, stream>>>(agg, x, W1l, b1, W1r,
                                                    nullptr, nullptr, out, N);

    // layer 2 + fused final fc (reads h1 from d_out, overwrites d_out)
    aggregate_kernel<<<agg_blocks, 256, 0, stream>>>(out, csr, rs, cnt, inv, agg, N);
    gemm_kernel<1><<<gemm_blocks, 256, 0, stream>>>(agg, out, W2l, b2, W2r,
                                                    Wf, bf, out, N);
}

// Round 4
// 378.902 us; speedup vs baseline: 6.8438x; 1.0416x over previous
//
#include <hip/hip_runtime.h>

#define D 128
#define SCAN_B 256
#define BM 64
#define BK 32
#define HS_LD 132

// ---- degree count ----
__global__ void count_kernel(const int* __restrict__ ei, int E, int* __restrict__ cnt) {
    int t = blockIdx.x * blockDim.x + threadIdx.x;
    if (t < E) atomicAdd(&cnt[ei[E + t]], 1);
}

__global__ void inv_kernel(const int* __restrict__ cnt, float* __restrict__ inv, int N) {
    int t = blockIdx.x * blockDim.x + threadIdx.x;
    if (t < N) inv[t] = 1.0f / (float)max(cnt[t], 1);
}

// ---- hierarchical exclusive scan ----
__global__ void scan_pass1(const int* __restrict__ cnt, int* __restrict__ rs,
                           int* __restrict__ bsum, int N) {
    __shared__ int lds[SCAN_B];
    int tid = threadIdx.x;
    int i = blockIdx.x * SCAN_B + tid;
    int v = (i < N) ? cnt[i] : 0;
    lds[tid] = v;
    __syncthreads();
    for (int o = 1; o < SCAN_B; o <<= 1) {
        int t = (tid >= o) ? lds[tid - o] : 0;
        __syncthreads();
        lds[tid] += t;
        __syncthreads();
    }
    if (i < N) rs[i] = lds[tid] - v;
    if (tid == SCAN_B - 1) bsum[blockIdx.x] = lds[tid];
}

__global__ void scan_pass2(int* __restrict__ bsum, int nb) {
    __shared__ int lds[SCAN_B];
    int tid = threadIdx.x;
    int v = (tid < nb) ? bsum[tid] : 0;
    lds[tid] = v;
    __syncthreads();
    for (int o = 1; o < SCAN_B; o <<= 1) {
        int t = (tid >= o) ? lds[tid - o] : 0;
        __syncthreads();
        lds[tid] += t;
        __syncthreads();
    }
    if (tid < nb) bsum[tid] = lds[tid] - v;
}

__global__ void scan_pass3(int* __restrict__ rs, int* __restrict__ cursor,
                           const int* __restrict__ bsum, int N) {
    int i = blockIdx.x * SCAN_B + threadIdx.x;
    if (i < N) {
        int v = rs[i] + bsum[blockIdx.x];
        rs[i] = v;
        cursor[i] = v;
    }
}

__global__ void fill_kernel(const int* __restrict__ ei, int E,
                            int* __restrict__ cursor, int* __restrict__ csr) {
    int e = blockIdx.x * blockDim.x + threadIdx.x;
    if (e < E) {
        int src = ei[e], dst = ei[E + e];
        int pos = atomicAdd(&cursor[dst], 1);
        csr[pos] = src;
    }
}

// ---- gather-mean aggregate: 32 lanes per node, 4-way unrolled for MLP ----
__global__ void aggregate_kernel(const float* __restrict__ x, const int* __restrict__ csr,
                                 const int* __restrict__ rs, const int* __restrict__ cnt,
                                 const float* __restrict__ inv, float* __restrict__ agg,
                                 int N) {
    int t = blockIdx.x * blockDim.x + threadIdx.x;
    int node = t >> 5;
    int c = t & 31;
    if (node >= N) return;
    int deg = cnt[node];
    int st = rs[node];
    const float4* x4 = (const float4*)x;
    float4 s0 = make_float4(0.f, 0.f, 0.f, 0.f);
    float4 s1 = make_float4(0.f, 0.f, 0.f, 0.f);
    int i = 0;
    for (; i + 4 <= deg; i += 4) {
        int n0 = csr[st + i + 0];
        int n1 = csr[st + i + 1];
        int n2 = csr[st + i + 2];
        int n3 = csr[st + i + 3];
        float4 v0 = x4[(size_t)n0 * 32 + c];
        float4 v1 = x4[(size_t)n1 * 32 + c];
        float4 v2 = x4[(size_t)n2 * 32 + c];
        float4 v3 = x4[(size_t)n3 * 32 + c];
        s0.x += v0.x + v1.x; s0.y += v0.y + v1.y;
        s0.z += v0.z + v1.z; s0.w += v0.w + v1.w;
        s1.x += v2.x + v3.x; s1.y += v2.y + v3.y;
        s1.z += v2.z + v3.z; s1.w += v2.w + v3.w;
    }
    for (; i < deg; i++) {
        int n0 = csr[st + i];
        float4 v0 = x4[(size_t)n0 * 32 + c];
        s0.x += v0.x; s0.y += v0.y; s0.z += v0.z; s0.w += v0.w;
    }
    float iv = inv[node];
    float4 s = make_float4((s0.x + s1.x) * iv, (s0.y + s1.y) * iv,
                           (s0.z + s1.z) * iv, (s0.w + s1.w) * iv);
    ((float4*)agg)[(size_t)node * 32 + c] = s;
}

// ---- register-tiled fused GEMM, untransposed A ----
// C[64 x 128] = relu(l2norm([agg|x] @ [Wl;Wr] + bl)) [@ Wf + bf]
// 256 threads: tg=tid>>5 -> 8 nodes, tn=tid&31 -> 4 cols
template <int FUSE_FC>
__global__ __launch_bounds__(256) void gemm_kernel(
        const float* __restrict__ agg, const float* __restrict__ x,
        const float* __restrict__ Wl, const float* __restrict__ bl,
        const float* __restrict__ Wr,
        const float* __restrict__ Wf, const float* __restrict__ bf,
        float* __restrict__ out, int N) {
    // smem: As[64][32]=2048f | Ws[32][128]=4096f  (6144f = 24576B)
    // FUSE_FC: Hs[64][132]=8448f overlaps both (33792B)
    constexpr int SMEM_F = FUSE_FC ? (BM * HS_LD) : (BM * BK + BK * D);
    __shared__ float smem[SMEM_F];
    float* As = smem;               // [64][32]
    float* Ws = smem + BM * BK;     // [32][128]

    const int tid = threadIdx.x;
    const int tn = tid & 31;
    const int tg = tid >> 5;
    const int m_base = tg * 8;
    const int n_base = tn * 4;
    const int mb = blockIdx.x * BM;

    float acc[8][4];
#pragma unroll
    for (int i = 0; i < 8; i++)
#pragma unroll
        for (int j = 0; j < 4; j++) acc[i][j] = 0.0f;

    for (int kk = 0; kk < 2 * D; kk += BK) {
        const float* Ab = (kk < D) ? agg : x;
        const float* Wb = (kk < D) ? Wl : Wr;
        const int kl = kk & (D - 1);
        // stage A tile straight: 512 float4, 2 per thread
#pragma unroll
        for (int r = 0; r < 2; r++) {
            int f = tid + r * 256;
            int m = f >> 3, kq = f & 7;
            int ng = mb + m;
            if (ng >= N) ng = N - 1;
            float4 v = ((const float4*)Ab)[(size_t)ng * 32 + (kl >> 2) + kq];
            *((float4*)&As[m * BK + kq * 4]) = v;
        }
        // stage W tile: 1024 float4, 4 per thread
#pragma unroll
        for (int r = 0; r < 4; r++) {
            int f = tid + r * 256;
            int k = f >> 5, nq = f & 31;
            ((float4*)Ws)[k * 32 + nq] = ((const float4*)Wb)[(size_t)(kl + k) * 32 + nq];
        }
        __syncthreads();
#pragma unroll
        for (int k4 = 0; k4 < BK / 4; k4++) {
            float4 w0 = *((const float4*)&Ws[(k4 * 4 + 0) * D + n_base]);
            float4 w1 = *((const float4*)&Ws[(k4 * 4 + 1) * D + n_base]);
            float4 w2 = *((const float4*)&Ws[(k4 * 4 + 2) * D + n_base]);
            float4 w3 = *((const float4*)&Ws[(k4 * 4 + 3) * D + n_base]);
#pragma unroll
            for (int mi = 0; mi < 8; mi++) {
                float4 a = *((const float4*)&As[(m_base + mi) * BK + k4 * 4]);
                acc[mi][0] = fmaf(a.x, w0.x, acc[mi][0]);
                acc[mi][1] = fmaf(a.x, w0.y, acc[mi][1]);
                acc[mi][2] = fmaf(a.x, w0.z, acc[mi][2]);
                acc[mi][3] = fmaf(a.x, w0.w, acc[mi][3]);
                acc[mi][0] = fmaf(a.y, w1.x, acc[mi][0]);
                acc[mi][1] = fmaf(a.y, w1.y, acc[mi][1]);
                acc[mi][2] = fmaf(a.y, w1.z, acc[mi][2]);
                acc[mi][3] = fmaf(a.y, w1.w, acc[mi][3]);
                acc[mi][0] = fmaf(a.z, w2.x, acc[mi][0]);
                acc[mi][1] = fmaf(a.z, w2.y, acc[mi][1]);
                acc[mi][2] = fmaf(a.z, w2.z, acc[mi][2]);
                acc[mi][3] = fmaf(a.z, w2.w, acc[mi][3]);
                acc[mi][0] = fmaf(a.w, w3.x, acc[mi][0]);
                acc[mi][1] = fmaf(a.w, w3.y, acc[mi][1]);
                acc[mi][2] = fmaf(a.w, w3.z, acc[mi][2]);
                acc[mi][3] = fmaf(a.w, w3.w, acc[mi][3]);
            }
        }
        __syncthreads();
    }

    // epilogue: bias + per-node L2 norm (32-lane reduction) + relu
    const float4 blv = ((const float4*)bl)[tn];
    float h[8][4];
#pragma unroll
    for (int mi = 0; mi < 8; mi++) {
        float v0 = acc[mi][0] + blv.x;
        float v1 = acc[mi][1] + blv.y;
        float v2 = acc[mi][2] + blv.z;
        float v3 = acc[mi][3] + blv.w;
        float s = v0 * v0 + v1 * v1 + v2 * v2 + v3 * v3;
#pragma unroll
        for (int o = 16; o > 0; o >>= 1) s += __shfl_xor(s, o, 32);
        float rn = 1.0f / fmaxf(sqrtf(s), 1e-12f);
        h[mi][0] = fmaxf(v0 * rn, 0.0f);
        h[mi][1] = fmaxf(v1 * rn, 0.0f);
        h[mi][2] = fmaxf(v2 * rn, 0.0f);
        h[mi][3] = fmaxf(v3 * rn, 0.0f);
    }

    if (!FUSE_FC) {
#pragma unroll
        for (int mi = 0; mi < 8; mi++) {
            int node = mb + m_base + mi;
            if (node < N) {
                float4 o4 = make_float4(h[mi][0], h[mi][1], h[mi][2], h[mi][3]);
                ((float4*)out)[(size_t)node * 32 + tn] = o4;
            }
        }
        return;
    }

    // FC: Hs reuses As/Ws space (last __syncthreads fenced all readers);
    // Wf read directly from global (L1/L2-hot).
    float* Hs = smem;  // [64][HS_LD]
#pragma unroll
    for (int mi = 0; mi < 8; mi++) {
        float4 o4 = make_float4(h[mi][0], h[mi][1], h[mi][2], h[mi][3]);
        *((float4*)&Hs[(m_base + mi) * HS_LD + n_base]) = o4;
    }
    __syncthreads();

    const float4 bfv = ((const float4*)bf)[tn];
    float acc2[8][4];
#pragma unroll
    for (int mi = 0; mi < 8; mi++) {
        acc2[mi][0] = bfv.x; acc2[mi][1] = bfv.y;
        acc2[mi][2] = bfv.z; acc2[mi][3] = bfv.w;
    }

#pragma unroll 4
    for (int k4 = 0; k4 < D / 4; k4++) {
        float4 w0 = ((const float4*)Wf)[(size_t)(k4 * 4 + 0) * 32 + tn];
        float4 w1 = ((const float4*)Wf)[(size_t)(k4 * 4 + 1) * 32 + tn];
        float4 w2 = ((const float4*)Wf)[(size_t)(k4 * 4 + 2) * 32 + tn];
        float4 w3 = ((const float4*)Wf)[(size_t)(k4 * 4 + 3) * 32 + tn];
#pragma unroll
        for (int mi = 0; mi < 8; mi++) {
            float4 a = *((const float4*)&Hs[(m_base + mi) * HS_LD + k4 * 4]);
            acc2[mi][0] = fmaf(a.x, w0.x, acc2[mi][0]);
            acc2[mi][1] = fmaf(a.x, w0.y, acc2[mi][1]);
            acc2[mi][2] = fmaf(a.x, w0.z, acc2[mi][2]);
            acc2[mi][3] = fmaf(a.x, w0.w, acc2[mi][3]);
            acc2[mi][0] = fmaf(a.y, w1.x, acc2[mi][0]);
            acc2[mi][1] = fmaf(a.y, w1.y, acc2[mi][1]);
            acc2[mi][2] = fmaf(a.y, w1.z, acc2[mi][2]);
            acc2[mi][3] = fmaf(a.y, w1.w, acc2[mi][3]);
            acc2[mi][0] = fmaf(a.z, w2.x, acc2[mi][0]);
            acc2[mi][1] = fmaf(a.z, w2.y, acc2[mi][1]);
            acc2[mi][2] = fmaf(a.z, w2.z, acc2[mi][2]);
            acc2[mi][3] = fmaf(a.z, w2.w, acc2[mi][3]);
            acc2[mi][0] = fmaf(a.w, w3.x, acc2[mi][0]);
            acc2[mi][1] = fmaf(a.w, w3.y, acc2[mi][1]);
            acc2[mi][2] = fmaf(a.w, w3.z, acc2[mi][2]);
            acc2[mi][3] = fmaf(a.w, w3.w, acc2[mi][3]);
        }
    }

#pragma unroll
    for (int mi = 0; mi < 8; mi++) {
        int node = mb + m_base + mi;
        if (node < N) {
            float4 o4 = make_float4(acc2[mi][0], acc2[mi][1], acc2[mi][2], acc2[mi][3]);
            ((float4*)out)[(size_t)node * 32 + tn] = o4;
        }
    }
}

extern "C" void kernel_launch(void* const* d_in, const int* in_sizes, int n_in,
                              void* d_out, int out_size, void* d_ws, size_t ws_size,
                              hipStream_t stream) {
    const float* x   = (const float*)d_in[0];
    const int*   ei  = (const int*)d_in[1];
    const float* W1l = (const float*)d_in[2];
    const float* b1  = (const float*)d_in[3];
    const float* W1r = (const float*)d_in[4];
    const float* W2l = (const float*)d_in[5];
    const float* b2  = (const float*)d_in[6];
    const float* W2r = (const float*)d_in[7];
    const float* Wf  = (const float*)d_in[8];
    const float* bf  = (const float*)d_in[9];
    float* out = (float*)d_out;

    int N = in_sizes[0] / D;
    int E = in_sizes[1] / 2;

    // ws layout: agg[N*D] f | inv[N] f | rs[N] i | cnt[N] i | cursor[N] i | bsum[256] i | csr[E] i
    float* ws     = (float*)d_ws;
    float* agg    = ws;
    float* inv    = ws + (size_t)N * D;
    int*   rs     = (int*)(inv + N);
    int*   cnt    = rs + N;
    int*   cursor = cnt + N;
    int*   bsum   = cursor + N;
    int*   csr    = bsum + 256;

    int nb = (N + SCAN_B - 1) / SCAN_B;

    hipMemsetAsync(cnt, 0, (size_t)N * sizeof(int), stream);
    count_kernel<<<(E + 255) / 256, 256, 0, stream>>>(ei, E, cnt);
    inv_kernel<<<nb, SCAN_B, 0, stream>>>(cnt, inv, N);
    scan_pass1<<<nb, SCAN_B, 0, stream>>>(cnt, rs, bsum, N);
    scan_pass2<<<1, SCAN_B, 0, stream>>>(bsum, nb);
    scan_pass3<<<nb, SCAN_B, 0, stream>>>(rs, cursor, bsum, N);
    fill_kernel<<<(E + 255) / 256, 256, 0, stream>>>(ei, E, cursor, csr);

    int agg_blocks = (N * 32 + 255) / 256;
    int gemm_blocks = (N + BM - 1) / BM;

    // layer 1 (h1 lives in d_out)
    aggregate_kernel<<<agg_blocks, 256, 0, stream>>>(x, csr, rs, cnt, inv, agg, N);
    gemm_kernel<0><<<gemm_blocks, 256, 0, stream>>>(agg, x, W1l, b1, W1r,
                                                    nullptr, nullptr, out, N);

    // layer 2 + fused final fc (reads h1 from d_out, overwrites d_out)
    aggregate_kernel<<<agg_blocks, 256, 0, stream>>>(out, csr, rs, cnt, inv, agg, N);
    gemm_kernel<1><<<gemm_blocks, 256, 0, stream>>>(agg, out, W2l, b2, W2r,
                                                    Wf, bf, out, N);
}

// Round 5
// 367.624 us; speedup vs baseline: 7.0538x; 1.0307x over previous
//
#include <hip/hip_runtime.h>

#define D 128
#define SCAN_B 256
#define BM 32
#define BK 32
#define HS_LD 132

// ---- degree count ----
__global__ void count_kernel(const int* __restrict__ ei, int E, int* __restrict__ cnt) {
    int t = blockIdx.x * blockDim.x + threadIdx.x;
    if (t < E) atomicAdd(&cnt[ei[E + t]], 1);
}

__global__ void inv_kernel(const int* __restrict__ cnt, float* __restrict__ inv, int N) {
    int t = blockIdx.x * blockDim.x + threadIdx.x;
    if (t < N) inv[t] = 1.0f / (float)max(cnt[t], 1);
}

// ---- hierarchical exclusive scan ----
__global__ void scan_pass1(const int* __restrict__ cnt, int* __restrict__ rs,
                           int* __restrict__ bsum, int N) {
    __shared__ int lds[SCAN_B];
    int tid = threadIdx.x;
    int i = blockIdx.x * SCAN_B + tid;
    int v = (i < N) ? cnt[i] : 0;
    lds[tid] = v;
    __syncthreads();
    for (int o = 1; o < SCAN_B; o <<= 1) {
        int t = (tid >= o) ? lds[tid - o] : 0;
        __syncthreads();
        lds[tid] += t;
        __syncthreads();
    }
    if (i < N) rs[i] = lds[tid] - v;
    if (tid == SCAN_B - 1) bsum[blockIdx.x] = lds[tid];
}

__global__ void scan_pass2(int* __restrict__ bsum, int nb) {
    __shared__ int lds[SCAN_B];
    int tid = threadIdx.x;
    int v = (tid < nb) ? bsum[tid] : 0;
    lds[tid] = v;
    __syncthreads();
    for (int o = 1; o < SCAN_B; o <<= 1) {
        int t = (tid >= o) ? lds[tid - o] : 0;
        __syncthreads();
        lds[tid] += t;
        __syncthreads();
    }
    if (tid < nb) bsum[tid] = lds[tid] - v;
}

__global__ void scan_pass3(int* __restrict__ rs, int* __restrict__ cursor,
                           const int* __restrict__ bsum, int N) {
    int i = blockIdx.x * SCAN_B + threadIdx.x;
    if (i < N) {
        int v = rs[i] + bsum[blockIdx.x];
        rs[i] = v;
        cursor[i] = v;
    }
}

__global__ void fill_kernel(const int* __restrict__ ei, int E,
                            int* __restrict__ cursor, int* __restrict__ csr) {
    int e = blockIdx.x * blockDim.x + threadIdx.x;
    if (e < E) {
        int src = ei[e], dst = ei[E + e];
        int pos = atomicAdd(&cursor[dst], 1);
        csr[pos] = src;
    }
}

// ---- gather-mean aggregate: 32 lanes per node, 4-way unrolled ----
__global__ void aggregate_kernel(const float* __restrict__ x, const int* __restrict__ csr,
                                 const int* __restrict__ rs, const int* __restrict__ cnt,
                                 const float* __restrict__ inv, float* __restrict__ agg,
                                 int N) {
    int t = blockIdx.x * blockDim.x + threadIdx.x;
    int node = t >> 5;
    int c = t & 31;
    if (node >= N) return;
    int deg = cnt[node];
    int st = rs[node];
    const float4* x4 = (const float4*)x;
    float4 s0 = make_float4(0.f, 0.f, 0.f, 0.f);
    float4 s1 = make_float4(0.f, 0.f, 0.f, 0.f);
    int i = 0;
    for (; i + 4 <= deg; i += 4) {
        int n0 = csr[st + i + 0];
        int n1 = csr[st + i + 1];
        int n2 = csr[st + i + 2];
        int n3 = csr[st + i + 3];
        float4 v0 = x4[(size_t)n0 * 32 + c];
        float4 v1 = x4[(size_t)n1 * 32 + c];
        float4 v2 = x4[(size_t)n2 * 32 + c];
        float4 v3 = x4[(size_t)n3 * 32 + c];
        s0.x += v0.x + v1.x; s0.y += v0.y + v1.y;
        s0.z += v0.z + v1.z; s0.w += v0.w + v1.w;
        s1.x += v2.x + v3.x; s1.y += v2.y + v3.y;
        s1.z += v2.z + v3.z; s1.w += v2.w + v3.w;
    }
    for (; i < deg; i++) {
        int n0 = csr[st + i];
        float4 v0 = x4[(size_t)n0 * 32 + c];
        s0.x += v0.x; s0.y += v0.y; s0.z += v0.z; s0.w += v0.w;
    }
    float iv = inv[node];
    float4 s = make_float4((s0.x + s1.x) * iv, (s0.y + s1.y) * iv,
                           (s0.z + s1.z) * iv, (s0.w + s1.w) * iv);
    ((float4*)agg)[(size_t)node * 32 + c] = s;
}

// ---- register-tiled fused GEMM, BM=32, thread tile 4x4 ----
// C[32 x 128] = relu(l2norm([agg|x] @ [Wl;Wr] + bl)) [@ Wf + bf]
// 256 threads: tg=tid>>5 -> 4 nodes, tn=tid&31 -> 4 cols
template <int FUSE_FC>
__global__ __launch_bounds__(256) void gemm_kernel(
        const float* __restrict__ agg, const float* __restrict__ x,
        const float* __restrict__ Wl, const float* __restrict__ bl,
        const float* __restrict__ Wr,
        const float* __restrict__ Wf, const float* __restrict__ bf,
        float* __restrict__ out, int N) {
    // smem: As[32][32]=1024f | Ws[32][128]=4096f -> 5120f = 20480B
    // FUSE_FC: Hs[32][132]=4224f overlaps (still 5120f)
    __shared__ float smem[BM * BK + BK * D];
    float* As = smem;               // [32][32]
    float* Ws = smem + BM * BK;     // [32][128]

    const int tid = threadIdx.x;
    const int tn = tid & 31;
    const int tg = tid >> 5;
    const int m_base = tg * 4;
    const int n_base = tn * 4;
    const int mb = blockIdx.x * BM;

    float acc[4][4];
#pragma unroll
    for (int i = 0; i < 4; i++)
#pragma unroll
        for (int j = 0; j < 4; j++) acc[i][j] = 0.0f;

    for (int kk = 0; kk < 2 * D; kk += BK) {
        const float* Ab = (kk < D) ? agg : x;
        const float* Wb = (kk < D) ? Wl : Wr;
        const int kl = kk & (D - 1);
        // stage A tile: 256 float4, 1 per thread
        {
            int m = tid >> 3, kq = tid & 7;
            int ng = mb + m;
            if (ng >= N) ng = N - 1;
            float4 v = ((const float4*)Ab)[(size_t)ng * 32 + (kl >> 2) + kq];
            *((float4*)&As[m * BK + kq * 4]) = v;
        }
        // stage W tile: 1024 float4, 4 per thread
#pragma unroll
        for (int r = 0; r < 4; r++) {
            int f = tid + r * 256;
            int k = f >> 5, nq = f & 31;
            ((float4*)Ws)[k * 32 + nq] = ((const float4*)Wb)[(size_t)(kl + k) * 32 + nq];
        }
        __syncthreads();
#pragma unroll
        for (int k4 = 0; k4 < BK / 4; k4++) {
            float4 w0 = *((const float4*)&Ws[(k4 * 4 + 0) * D + n_base]);
            float4 w1 = *((const float4*)&Ws[(k4 * 4 + 1) * D + n_base]);
            float4 w2 = *((const float4*)&Ws[(k4 * 4 + 2) * D + n_base]);
            float4 w3 = *((const float4*)&Ws[(k4 * 4 + 3) * D + n_base]);
#pragma unroll
            for (int mi = 0; mi < 4; mi++) {
                float4 a = *((const float4*)&As[(m_base + mi) * BK + k4 * 4]);
                acc[mi][0] = fmaf(a.x, w0.x, acc[mi][0]);
                acc[mi][1] = fmaf(a.x, w0.y, acc[mi][1]);
                acc[mi][2] = fmaf(a.x, w0.z, acc[mi][2]);
                acc[mi][3] = fmaf(a.x, w0.w, acc[mi][3]);
                acc[mi][0] = fmaf(a.y, w1.x, acc[mi][0]);
                acc[mi][1] = fmaf(a.y, w1.y, acc[mi][1]);
                acc[mi][2] = fmaf(a.y, w1.z, acc[mi][2]);
                acc[mi][3] = fmaf(a.y, w1.w, acc[mi][3]);
                acc[mi][0] = fmaf(a.z, w2.x, acc[mi][0]);
                acc[mi][1] = fmaf(a.z, w2.y, acc[mi][1]);
                acc[mi][2] = fmaf(a.z, w2.z, acc[mi][2]);
                acc[mi][3] = fmaf(a.z, w2.w, acc[mi][3]);
                acc[mi][0] = fmaf(a.w, w3.x, acc[mi][0]);
                acc[mi][1] = fmaf(a.w, w3.y, acc[mi][1]);
                acc[mi][2] = fmaf(a.w, w3.z, acc[mi][2]);
                acc[mi][3] = fmaf(a.w, w3.w, acc[mi][3]);
            }
        }
        __syncthreads();
    }

    // epilogue: bias + per-node L2 norm (32-lane reduction) + relu
    const float4 blv = ((const float4*)bl)[tn];
    float h[4][4];
#pragma unroll
    for (int mi = 0; mi < 4; mi++) {
        float v0 = acc[mi][0] + blv.x;
        float v1 = acc[mi][1] + blv.y;
        float v2 = acc[mi][2] + blv.z;
        float v3 = acc[mi][3] + blv.w;
        float s = v0 * v0 + v1 * v1 + v2 * v2 + v3 * v3;
#pragma unroll
        for (int o = 16; o > 0; o >>= 1) s += __shfl_xor(s, o, 32);
        float rn = 1.0f / fmaxf(sqrtf(s), 1e-12f);
        h[mi][0] = fmaxf(v0 * rn, 0.0f);
        h[mi][1] = fmaxf(v1 * rn, 0.0f);
        h[mi][2] = fmaxf(v2 * rn, 0.0f);
        h[mi][3] = fmaxf(v3 * rn, 0.0f);
    }

    if (!FUSE_FC) {
#pragma unroll
        for (int mi = 0; mi < 4; mi++) {
            int node = mb + m_base + mi;
            if (node < N) {
                float4 o4 = make_float4(h[mi][0], h[mi][1], h[mi][2], h[mi][3]);
                ((float4*)out)[(size_t)node * 32 + tn] = o4;
            }
        }
        return;
    }

    // FC: Hs reuses As/Ws space; Wf streamed from global (L1/L2-hot).
    float* Hs = smem;  // [32][HS_LD]
#pragma unroll
    for (int mi = 0; mi < 4; mi++) {
        float4 o4 = make_float4(h[mi][0], h[mi][1], h[mi][2], h[mi][3]);
        *((float4*)&Hs[(m_base + mi) * HS_LD + n_base]) = o4;
    }
    __syncthreads();

    const float4 bfv = ((const float4*)bf)[tn];
    float acc2[4][4];
#pragma unroll
    for (int mi = 0; mi < 4; mi++) {
        acc2[mi][0] = bfv.x; acc2[mi][1] = bfv.y;
        acc2[mi][2] = bfv.z; acc2[mi][3] = bfv.w;
    }

#pragma unroll 4
    for (int k4 = 0; k4 < D / 4; k4++) {
        float4 w0 = ((const float4*)Wf)[(size_t)(k4 * 4 + 0) * 32 + tn];
        float4 w1 = ((const float4*)Wf)[(size_t)(k4 * 4 + 1) * 32 + tn];
        float4 w2 = ((const float4*)Wf)[(size_t)(k4 * 4 + 2) * 32 + tn];
        float4 w3 = ((const float4*)Wf)[(size_t)(k4 * 4 + 3) * 32 + tn];
#pragma unroll
        for (int mi = 0; mi < 4; mi++) {
            float4 a = *((const float4*)&Hs[(m_base + mi) * HS_LD + k4 * 4]);
            acc2[mi][0] = fmaf(a.x, w0.x, acc2[mi][0]);
            acc2[mi][1] = fmaf(a.x, w0.y, acc2[mi][1]);
            acc2[mi][2] = fmaf(a.x, w0.z, acc2[mi][2]);
            acc2[mi][3] = fmaf(a.x, w0.w, acc2[mi][3]);
            acc2[mi][0] = fmaf(a.y, w1.x, acc2[mi][0]);
            acc2[mi][1] = fmaf(a.y, w1.y, acc2[mi][1]);
            acc2[mi][2] = fmaf(a.y, w1.z, acc2[mi][2]);
            acc2[mi][3] = fmaf(a.y, w1.w, acc2[mi][3]);
            acc2[mi][0] = fmaf(a.z, w2.x, acc2[mi][0]);
            acc2[mi][1] = fmaf(a.z, w2.y, acc2[mi][1]);
            acc2[mi][2] = fmaf(a.z, w2.z, acc2[mi][2]);
            acc2[mi][3] = fmaf(a.z, w2.w, acc2[mi][3]);
            acc2[mi][0] = fmaf(a.w, w3.x, acc2[mi][0]);
            acc2[mi][1] = fmaf(a.w, w3.y, acc2[mi][1]);
            acc2[mi][2] = fmaf(a.w, w3.z, acc2[mi][2]);
            acc2[mi][3] = fmaf(a.w, w3.w, acc2[mi][3]);
        }
    }

#pragma unroll
    for (int mi = 0; mi < 4; mi++) {
        int node = mb + m_base + mi;
        if (node < N) {
            float4 o4 = make_float4(acc2[mi][0], acc2[mi][1], acc2[mi][2], acc2[mi][3]);
            ((float4*)out)[(size_t)node * 32 + tn] = o4;
        }
    }
}

extern "C" void kernel_launch(void* const* d_in, const int* in_sizes, int n_in,
                              void* d_out, int out_size, void* d_ws, size_t ws_size,
                              hipStream_t stream) {
    const float* x   = (const float*)d_in[0];
    const int*   ei  = (const int*)d_in[1];
    const float* W1l = (const float*)d_in[2];
    const float* b1  = (const float*)d_in[3];
    const float* W1r = (const float*)d_in[4];
    const float* W2l = (const float*)d_in[5];
    const float* b2  = (const float*)d_in[6];
    const float* W2r = (const float*)d_in[7];
    const float* Wf  = (const float*)d_in[8];
    const float* bf  = (const float*)d_in[9];
    float* out = (float*)d_out;

    int N = in_sizes[0] / D;
    int E = in_sizes[1] / 2;

    // ws layout: agg[N*D] f | inv[N] f | rs[N] i | cnt[N] i | cursor[N] i | bsum[256] i | csr[E] i
    float* ws     = (float*)d_ws;
    float* agg    = ws;
    float* inv    = ws + (size_t)N * D;
    int*   rs     = (int*)(inv + N);
    int*   cnt    = rs + N;
    int*   cursor = cnt + N;
    int*   bsum   = cursor + N;
    int*   csr    = bsum + 256;

    int nb = (N + SCAN_B - 1) / SCAN_B;

    hipMemsetAsync(cnt, 0, (size_t)N * sizeof(int), stream);
    count_kernel<<<(E + 255) / 256, 256, 0, stream>>>(ei, E, cnt);
    inv_kernel<<<nb, SCAN_B, 0, stream>>>(cnt, inv, N);
    scan_pass1<<<nb, SCAN_B, 0, stream>>>(cnt, rs, bsum, N);
    scan_pass2<<<1, SCAN_B, 0, stream>>>(bsum, nb);
    scan_pass3<<<nb, SCAN_B, 0, stream>>>(rs, cursor, bsum, N);
    fill_kernel<<<(E + 255) / 256, 256, 0, stream>>>(ei, E, cursor, csr);

    int agg_blocks = (N * 32 + 255) / 256;
    int gemm_blocks = (N + BM - 1) / BM;

    // layer 1 (h1 lives in d_out)
    aggregate_kernel<<<agg_blocks, 256, 0, stream>>>(x, csr, rs, cnt, inv, agg, N);
    gemm_kernel<0><<<gemm_blocks, 256, 0, stream>>>(agg, x, W1l, b1, W1r,
                                                    nullptr, nullptr, out, N);

    // layer 2 + fused final fc (reads h1 from d_out, overwrites d_out)
    aggregate_kernel<<<agg_blocks, 256, 0, stream>>>(out, csr, rs, cnt, inv, agg, N);
    gemm_kernel<1><<<gemm_blocks, 256, 0, stream>>>(agg, out, W2l, b2, W2r,
                                                    Wf, bf, out, N);
}